// Round 8
// baseline (351.056 us; speedup 1.0000x reference)
//
#include <hip/hip_runtime.h>
#include <math.h>

#define HH 384
#define WW 384
#define NG 16
#define HW (HH*WW)

// tiles: 32 wide x 16 tall, 128 threads = (8 xg, 16 yy), 4 px/thread
#define FTW 32
#define FTH 16

// ---------------------------------------------------------------------------
// 13-tap (maskB) accumulate: a[oc][p] += W[oc][r*5+c] * row[c+p]
// ---------------------------------------------------------------------------
template <int PITCH>
__device__ __forceinline__ void accum13(const float* __restrict__ P,
                                        int ty, int tx0,
                                        float (&a)[3][4],
                                        const float (&Wl)[3][13])
{
#pragma unroll
    for (int r = 0; r < 3; ++r) {
        const float* row = P + (ty + r) * PITCH + tx0;
        float4 u0 = *(const float4*)(row);
        float4 u1 = *(const float4*)(row + 4);
        float v[8] = {u0.x, u0.y, u0.z, u0.w, u1.x, u1.y, u1.z, u1.w};
        const int cmax = (r < 2) ? 5 : 3;
#pragma unroll
        for (int c = 0; c < 5; ++c) {
            if (c >= cmax) break;
#pragma unroll
            for (int oc = 0; oc < 3; ++oc) {
                float w = Wl[oc][r * 5 + c];
#pragma unroll
                for (int p = 0; p < 4; ++p)
                    a[oc][p] += w * v[c + p];
            }
        }
    }
}

// ---------------------------------------------------------------------------
// Layer 1: x = data - 3.5 ; h = relu(gconv(x, w1*maskA, b1))
// maskA taps: rows 0,1 all 5 cols; row 2 cols 0,1 (12 taps).
// ---------------------------------------------------------------------------
__global__ __launch_bounds__(128) void conv1_kernel(
    const int* __restrict__ data, const float* __restrict__ w1,
    const float* __restrict__ b1, float* __restrict__ h)
{
    const int g  = blockIdx.z;
    const int x0 = blockIdx.x * FTW, y0 = blockIdx.y * FTH;
    __shared__ __align__(16) float s_in[FTH + 2][FTW + 8];
    const int tid = threadIdx.y * 8 + threadIdx.x;

    const float* wg = w1 + (size_t)g * 3 * 25;
    const float* bg = b1 + (size_t)g * 3;

    // stage 18 rows x 40 cols (origin y0-2, x0-4)
    const int* plane = data + g * HW;
    for (int i = tid; i < 18 * 10; i += 128) {
        int rr = i / 10, q = i % 10;
        int gy = y0 - 2 + rr, gx0 = x0 - 4 + 4 * q;
        float4 v = make_float4(0.f, 0.f, 0.f, 0.f);
        if (gy >= 0) {
            const int* rowp = plane + gy * WW;
            if (gx0 >= 0 && gx0 + 3 < WW) {
                int4 iv = *(const int4*)(rowp + gx0);
                v = make_float4((float)iv.x - 3.5f, (float)iv.y - 3.5f,
                                (float)iv.z - 3.5f, (float)iv.w - 3.5f);
            } else {
                float t[4];
#pragma unroll
                for (int p = 0; p < 4; ++p) {
                    int gx = gx0 + p;
                    t[p] = (gx >= 0 && gx < WW) ? (float)rowp[gx] - 3.5f : 0.f;
                }
                v = make_float4(t[0], t[1], t[2], t[3]);
            }
        }
        *(float4*)&s_in[rr][4 * q] = v;
    }
    __syncthreads();

    const int xg = threadIdx.x, yy = threadIdx.y;
    float a[3][4];
#pragma unroll
    for (int oc = 0; oc < 3; ++oc)
#pragma unroll
        for (int p = 0; p < 4; ++p) a[oc][p] = bg[oc];

#pragma unroll
    for (int r = 0; r < 3; ++r) {
        const float* row = &s_in[yy + r][4 * xg];
        float4 u0 = *(const float4*)(row);
        float4 u1 = *(const float4*)(row + 4);
        float4 u2 = *(const float4*)(row + 8);
        float v[12] = {u0.x, u0.y, u0.z, u0.w, u1.x, u1.y, u1.z, u1.w,
                       u2.x, u2.y, u2.z, u2.w};
        const int cmax = (r < 2) ? 5 : 2;      // maskA
#pragma unroll
        for (int c = 0; c < 5; ++c) {
            if (c >= cmax) break;
#pragma unroll
            for (int oc = 0; oc < 3; ++oc) {
                float w = wg[oc * 25 + r * 5 + c];
#pragma unroll
                for (int p = 0; p < 4; ++p)
                    a[oc][p] += w * v[c + p + 2];   // input origin x0-4
            }
        }
    }
    const int gy = y0 + yy;
    float* ob = h + (size_t)g * 3 * HW + (size_t)gy * WW + x0 + 4 * xg;
#pragma unroll
    for (int oc = 0; oc < 3; ++oc) {
        *(float4*)(ob + (size_t)oc * HW) =
            make_float4(fmaxf(a[oc][0], 0.f), fmaxf(a[oc][1], 0.f),
                        fmaxf(a[oc][2], 0.f), fmaxf(a[oc][3], 0.f));
    }
}

// ---------------------------------------------------------------------------
// Fused residual block: out = in + relu(convB(relu(convB(in, wa)), wb))
// IN origin (y0-4, x0-4): [3][20][40]; T origin (y0-2, x0-2): [3][18][36].
// LDS = 17.0 KB -> 9 blocks/CU; grid 4608 = 18/CU -> two full generations.
// ---------------------------------------------------------------------------
__global__ __launch_bounds__(128) void res_block_kernel(
    const float* __restrict__ in, const float* __restrict__ wa,
    const float* __restrict__ ba, const float* __restrict__ wb,
    const float* __restrict__ bb, float* __restrict__ out)
{
    const int g  = blockIdx.z;
    const int x0 = blockIdx.x * FTW, y0 = blockIdx.y * FTH;
    __shared__ __align__(16) float IN[3][FTH + 4][FTW + 8];
    __shared__ __align__(16) float T [3][FTH + 2][FTW + 4];
    const int tid = threadIdx.y * 8 + threadIdx.x;

    const float* wga = wa + (size_t)g * 9 * 25;
    const float* bga = ba + (size_t)g * 3;
    const float* wgb = wb + (size_t)g * 9 * 25;
    const float* bgb = bb + (size_t)g * 3;

    // ---- stage input tile (3 ch x 20 rows x 10 quads = 600) ----
    const float* base = in + (size_t)g * 3 * HW;
    const bool interior = (y0 >= 4) && (x0 >= 4) && (x0 + 36 <= WW);
    if (interior) {
        for (int i = tid; i < 600; i += 128) {
            int ch = i / 200, rem = i % 200, rr = rem / 10, q = rem % 10;
            const float* rowp = base + (size_t)ch * HW
                              + (size_t)(y0 - 4 + rr) * WW + (x0 - 4 + 4 * q);
            *(float4*)&IN[ch][rr][4 * q] = *(const float4*)rowp;
        }
    } else {
        for (int i = tid; i < 600; i += 128) {
            int ch = i / 200, rem = i % 200, rr = rem / 10, q = rem % 10;
            int gy = y0 - 4 + rr, gx0 = x0 - 4 + 4 * q;
            float4 v = make_float4(0.f, 0.f, 0.f, 0.f);
            if (gy >= 0) {
                const float* rowp = base + (size_t)ch * HW + (size_t)gy * WW;
                if (gx0 >= 0 && gx0 + 3 < WW) {
                    v = *(const float4*)(rowp + gx0);
                } else {
                    float t[4];
#pragma unroll
                    for (int p = 0; p < 4; ++p) {
                        int gx = gx0 + p;
                        t[p] = (gx >= 0 && gx < WW) ? rowp[gx] : 0.f;
                    }
                    v = make_float4(t[0], t[1], t[2], t[3]);
                }
            }
            *(float4*)&IN[ch][rr][4 * q] = v;
        }
    }
    __syncthreads();

    // ---- first conv: T = relu(convB(IN)) over 18x36 region (162 quad-items) ----
#pragma unroll 1
    for (int it = 0; it < 2; ++it) {
        const int i = tid + (it << 7);
        if (i < 162) {
            const int ty = i / 9, tx0 = 4 * (i % 9);
            float a[3][4];
#pragma unroll
            for (int oc = 0; oc < 3; ++oc)
#pragma unroll
                for (int p = 0; p < 4; ++p) a[oc][p] = bga[oc];

#pragma unroll
            for (int ic = 0; ic < 3; ++ic) {
                float Wl[3][13];
#pragma unroll
                for (int oc = 0; oc < 3; ++oc)
#pragma unroll
                    for (int t = 0; t < 13; ++t)
                        Wl[oc][t] = wga[(oc * 3 + ic) * 25 + t];
                accum13<FTW + 8>(&IN[ic][0][0], ty, tx0, a, Wl);
            }

            const int gty = y0 - 2 + ty, gtx0 = x0 - 2 + tx0;
#pragma unroll
            for (int oc = 0; oc < 3; ++oc) {
                float r_[4];
#pragma unroll
                for (int p = 0; p < 4; ++p) {
                    int gx = gtx0 + p;
                    bool ok = (gty >= 0) && (gx >= 0) && (gx < WW);
                    r_[p] = ok ? fmaxf(a[oc][p], 0.f) : 0.f;
                }
                *(float4*)&T[oc][ty][tx0] = make_float4(r_[0], r_[1], r_[2], r_[3]);
            }
        }
    }
    __syncthreads();

    // ---- second conv + residual add + write (one quad per thread) ----
    const int xg = threadIdx.x, yy = threadIdx.y;
    float a[3][4];
#pragma unroll
    for (int oc = 0; oc < 3; ++oc)
#pragma unroll
        for (int p = 0; p < 4; ++p) a[oc][p] = bgb[oc];

#pragma unroll
    for (int ic = 0; ic < 3; ++ic) {
        float Wl[3][13];
#pragma unroll
        for (int oc = 0; oc < 3; ++oc)
#pragma unroll
            for (int t = 0; t < 13; ++t)
                Wl[oc][t] = wgb[(oc * 3 + ic) * 25 + t];
        accum13<FTW + 4>(&T[ic][0][0], yy, 4 * xg, a, Wl);
    }

    const int gy = y0 + yy;
    float* ob = out + (size_t)g * 3 * HW + (size_t)gy * WW + x0 + 4 * xg;
#pragma unroll
    for (int oc = 0; oc < 3; ++oc) {
        float4 h0 = *(const float4*)&IN[oc][yy + 4][4 * xg + 4];
        *(float4*)(ob + (size_t)oc * HW) =
            make_float4(h0.x + fmaxf(a[oc][0], 0.f), h0.y + fmaxf(a[oc][1], 0.f),
                        h0.z + fmaxf(a[oc][2], 0.f), h0.w + fmaxf(a[oc][3], 0.f));
    }
}

// ---------------------------------------------------------------------------
// Fast branchless transcendentals
// ---------------------------------------------------------------------------
__device__ __forceinline__ float fast_rcp(float x) {
    return __builtin_amdgcn_rcpf(x);
}

__device__ __forceinline__ float fast_softplus(float x) {
    float t = __expf(-fabsf(x));
    return fmaxf(x, 0.f) + __logf(1.f + t);
}

// ---------------------------------------------------------------------------
// Final conv (9 out ch per group) fused with mixture-CDF -> pmf * 65536.
// Phi(z) ~ 1/(1+exp(-(1.5976 z + 0.07056 z^3)))  (sigmoid CDF approx)
// IN origin (y0-2, x0-4): [3][18][40] = 8.6 KB -> 16 blocks/CU (wave-cap).
// ---------------------------------------------------------------------------
__global__ __launch_bounds__(128) void final_kernel(
    const float* __restrict__ hbuf, const float* __restrict__ wf,
    const float* __restrict__ bf, float* __restrict__ out)
{
    const int g  = blockIdx.z;
    const int x0 = blockIdx.x * FTW, y0 = blockIdx.y * FTH;
    __shared__ __align__(16) float IN[3][FTH + 2][FTW + 8];
    const int tid = threadIdx.y * 8 + threadIdx.x;

    const float* wg = wf + (size_t)g * 9 * 3 * 25;  // [m][ic][25]
    const float* bg = bf + (size_t)g * 9;

    const float* base = hbuf + (size_t)g * 3 * HW;
    const bool interior = (y0 >= 2) && (x0 >= 4) && (x0 + 36 <= WW);
    if (interior) {
        for (int i = tid; i < 540; i += 128) {
            int ch = i / 180, rem = i % 180, rr = rem / 10, q = rem % 10;
            const float* rowp = base + (size_t)ch * HW
                              + (size_t)(y0 - 2 + rr) * WW + (x0 - 4 + 4 * q);
            *(float4*)&IN[ch][rr][4 * q] = *(const float4*)rowp;
        }
    } else {
        for (int i = tid; i < 540; i += 128) {
            int ch = i / 180, rem = i % 180, rr = rem / 10, q = rem % 10;
            int gy = y0 - 2 + rr, gx0 = x0 - 4 + 4 * q;
            float4 v = make_float4(0.f, 0.f, 0.f, 0.f);
            if (gy >= 0) {
                const float* rowp = base + (size_t)ch * HW + (size_t)gy * WW;
                if (gx0 >= 0 && gx0 + 3 < WW) {
                    v = *(const float4*)(rowp + gx0);
                } else {
                    float t[4];
#pragma unroll
                    for (int p = 0; p < 4; ++p) {
                        int gx = gx0 + p;
                        t[p] = (gx >= 0 && gx < WW) ? rowp[gx] : 0.f;
                    }
                    v = make_float4(t[0], t[1], t[2], t[3]);
                }
            }
            *(float4*)&IN[ch][rr][4 * q] = v;
        }
    }
    __syncthreads();

    const int xg = threadIdx.x, yy = threadIdx.y;
    float P[9][4];
#pragma unroll
    for (int m = 0; m < 9; ++m) {
        float b = bg[m];
#pragma unroll
        for (int p = 0; p < 4; ++p) P[m][p] = b;
    }

#pragma unroll
    for (int ic = 0; ic < 3; ++ic) {
        float v[3][12];
#pragma unroll
        for (int r = 0; r < 3; ++r) {
            const float* row = &IN[ic][yy + r][4 * xg];
            float4 u0 = *(const float4*)(row);
            float4 u1 = *(const float4*)(row + 4);
            float4 u2 = *(const float4*)(row + 8);
            v[r][0] = u0.x; v[r][1] = u0.y; v[r][2]  = u0.z; v[r][3]  = u0.w;
            v[r][4] = u1.x; v[r][5] = u1.y; v[r][6]  = u1.z; v[r][7]  = u1.w;
            v[r][8] = u2.x; v[r][9] = u2.y; v[r][10] = u2.z; v[r][11] = u2.w;
        }
#pragma unroll
        for (int m = 0; m < 9; ++m) {
#pragma unroll
            for (int r = 0; r < 3; ++r) {
                const int cmax = (r < 2) ? 5 : 3;
#pragma unroll
                for (int c = 0; c < 5; ++c) {
                    if (c >= cmax) break;
                    float w = wg[(m * 3 + ic) * 25 + r * 5 + c];
#pragma unroll
                    for (int p = 0; p < 4; ++p)
                        P[m][p] += w * v[r][c + p + 2];   // IN origin x0-4
                }
            }
        }
    }

    // ---- mixture per pixel (sigmoid-CDF) ----
    float wm0[4], wm1[4], wm2[4], ks0[4], ks1[4], ks2[4], nm0[4], nm1[4], nm2[4];
#pragma unroll
    for (int p = 0; p < 4; ++p) {
        float lw0 = P[0][p], m0 = P[1][p], ls0 = P[2][p];
        float lw1 = P[3][p], m1 = P[4][p], ls1 = P[5][p];
        float lw2 = P[6][p], m2 = P[7][p], ls2 = P[8][p];
        float lmax = fmaxf(lw0, fmaxf(lw1, lw2));
        float e0 = __expf(lw0 - lmax), e1 = __expf(lw1 - lmax), e2 = __expf(lw2 - lmax);
        float inv_sum = fast_rcp(e0 + e1 + e2);
        wm0[p] = e0 * inv_sum;
        wm1[p] = e1 * inv_sum;
        wm2[p] = e2 * inv_sum;
        ks0[p] = fast_rcp(fast_softplus(ls0) + 1e-6f);   // 1/scale
        ks1[p] = fast_rcp(fast_softplus(ls1) + 1e-6f);
        ks2[p] = fast_rcp(fast_softplus(ls2) + 1e-6f);
        nm0[p] = -m0 * ks0[p];
        nm1[p] = -m1 * ks1[p];
        nm2[p] = -m2 * ks2[p];
    }

    const int gy = y0 + yy;
    float* ob = out + ((size_t)g * 8 * HH + gy) * WW + x0 + 4 * xg;
    float prev[4] = {0.f, 0.f, 0.f, 0.f};
#pragma unroll
    for (int j = 0; j <= 8; ++j) {
        float edge = (float)j - 4.0f;
        float cdf[4];
#pragma unroll
        for (int p = 0; p < 4; ++p) {
            float z0 = fmaf(edge, ks0[p], nm0[p]);
            float z1 = fmaf(edge, ks1[p], nm1[p]);
            float z2 = fmaf(edge, ks2[p], nm2[p]);
            float y0_ = z0 * fmaf(z0 * z0, -0.07056f, -1.5976f);
            float y1_ = z1 * fmaf(z1 * z1, -0.07056f, -1.5976f);
            float y2_ = z2 * fmaf(z2 * z2, -0.07056f, -1.5976f);
            float c = wm0[p] * fast_rcp(1.f + __expf(y0_));
            c = fmaf(wm1[p], fast_rcp(1.f + __expf(y1_)), c);
            c = fmaf(wm2[p], fast_rcp(1.f + __expf(y2_)), c);
            cdf[p] = c;
        }
        if (j > 0) {
            *(float4*)(ob + (size_t)(j - 1) * HW) =
                make_float4((cdf[0] - prev[0]) * 65536.f, (cdf[1] - prev[1]) * 65536.f,
                            (cdf[2] - prev[2]) * 65536.f, (cdf[3] - prev[3]) * 65536.f);
        }
#pragma unroll
        for (int p = 0; p < 4; ++p) prev[p] = cdf[p];
    }
}

// ---------------------------------------------------------------------------
extern "C" void kernel_launch(void* const* d_in, const int* in_sizes, int n_in,
                              void* d_out, int out_size, void* d_ws, size_t ws_size,
                              hipStream_t stream)
{
    const int*   data = (const int*)d_in[0];
    const float* w1   = (const float*)d_in[1];
    const float* b1   = (const float*)d_in[2];
    const float* rw   = (const float*)d_in[3];
    const float* rb   = (const float*)d_in[4];
    const float* wf   = (const float*)d_in[5];
    const float* bf   = (const float*)d_in[6];
    float* out = (float*)d_out;

    float* A = (float*)d_ws;
    float* B = A + (size_t)48 * HW;

    dim3 blk(8, 16, 1);
    dim3 grd(WW / FTW, HH / FTH, NG);   // 12 x 24 x 16 = 4608 blocks

    conv1_kernel<<<grd, blk, 0, stream>>>(data, w1, b1, A);

    const float* cur = A;
    float* nxt = B;
    for (int i = 0; i < 5; ++i) {
        const float* wa = rw + (size_t)(i * 2 + 0) * 48 * 3 * 25;
        const float* ba = rb + (i * 2 + 0) * 48;
        const float* wb = rw + (size_t)(i * 2 + 1) * 48 * 3 * 25;
        const float* bb = rb + (i * 2 + 1) * 48;
        res_block_kernel<<<grd, blk, 0, stream>>>(cur, wa, ba, wb, bb, nxt);
        const float* t = cur; cur = nxt; nxt = (float*)t;
    }
    final_kernel<<<grd, blk, 0, stream>>>(cur, wf, bf, out);
}